// Round 2
// baseline (2314.468 us; speedup 1.0000x reference)
//
#include <hip/hip_runtime.h>

typedef __attribute__((ext_vector_type(8))) short short8;
typedef __attribute__((ext_vector_type(4))) float floatx4;

__device__ __forceinline__ float b2f(short b) {
  union { unsigned u; float f; } v; v.u = ((unsigned)(unsigned short)b) << 16; return v.f;
}
__device__ __forceinline__ short f2b(float f) {
  union { float f; unsigned u; } v; v.f = f;
  return (short)((v.u + 0x7fffu + ((v.u >> 16) & 1u)) >> 16);
}
__device__ __forceinline__ float loadf(const void* p, size_t i, bool f32) {
  return f32 ? ((const float*)p)[i] : b2f(((const short*)p)[i]);
}
__device__ __forceinline__ short8 load8(const void* p, size_t i, bool f32) {
  if (f32) {
    const float* fp = (const float*)p + i;
    float4 a = *(const float4*)fp;
    float4 b = *(const float4*)(fp + 4);
    short8 r;
    r[0] = f2b(a.x); r[1] = f2b(a.y); r[2] = f2b(a.z); r[3] = f2b(a.w);
    r[4] = f2b(b.x); r[5] = f2b(b.y); r[6] = f2b(b.z); r[7] = f2b(b.w);
    return r;
  }
  return *(const short8*)((const short*)p + i);
}

// ---------- dtype detector: fp32 data read as shorts has random exponent fields
__global__ void detect_dtype(const unsigned short* __restrict__ w, int* __restrict__ flag) {
  __shared__ int cnt;
  if (threadIdx.x == 0) cnt = 0;
  __syncthreads();
  int bad = 0;
  for (int i = threadIdx.x; i < 4096; i += 256) {
    int e = (w[i] >> 7) & 0xFF;
    if (e >= 0xC8) bad++;  // |x| >= 2^73: impossible for real bf16 weights
  }
  atomicAdd(&cnt, bad);
  __syncthreads();
  if (threadIdx.x == 0) *flag = (cnt > 64) ? 1 : 0;
}

// ---------- GEMM: C[c_row0+M rows, N] = A[a_row0+.., K] @ B[K,N] (+bias)
// 128x128 tile, BK=32, 4 waves 2x2, 16x16x32 bf16 MFMA, fp32 acc.
// A/bias dtype: input-flag if aIn; B always input dtype; C fp32 iff (cOut && f32) else bf16.
__global__ __launch_bounds__(256, 2)
void gemm_bt(const void* __restrict__ A, int a_row0,
             const void* __restrict__ B, const void* __restrict__ bias,
             void* __restrict__ C, int c_row0, int N, int K,
             const int* __restrict__ dflag, int aIn, int cOut) {
  __shared__ short As[128 * 32];
  __shared__ short Bs[128 * 32];
  const bool f32 = (*dflag != 0);
  const bool a32 = aIn && f32;
  const bool c32 = cOut && f32;
  const int tid = threadIdx.x;
  const int lane = tid & 63, w = tid >> 6;
  const int wm = w & 1, wn = w >> 1;
  const int qg = lane >> 4, l16 = lane & 15;
  const int m0 = blockIdx.y << 7, n0 = blockIdx.x << 7;

  const int arow = tid >> 2, ak = (tid & 3) << 3;
  const int brow = tid >> 4, bc = (tid & 15) << 3;
  const int rot = tid & 15;

  floatx4 acc[4][4];
#pragma unroll
  for (int i = 0; i < 4; ++i)
#pragma unroll
    for (int j = 0; j < 4; ++j) acc[i][j] = (floatx4){0.f, 0.f, 0.f, 0.f};

  for (int k0 = 0; k0 < K; k0 += 32) {
    __syncthreads();
#pragma unroll
    for (int j = 0; j < 2; ++j) {
      short8 av = load8(A, (size_t)(a_row0 + m0 + j * 64 + arow) * K + (k0 + ak), a32);
      *(short8*)(As + (j * 64 + arow) * 32 + ak) = av;
      int kr = j * 16 + brow;  // tile-local k 0..31
      short8 bv = load8(B, (size_t)(k0 + kr) * N + (n0 + bc), f32);
      int kq = kr >> 3, kj = kr & 7;
#pragma unroll
      for (int s = 0; s < 8; ++s) {
        int u = (s + rot) & 7;  // rotate to spread banks
        int n = bc + u;
        Bs[(n << 5) + ((kq ^ (n & 3)) << 3) + kj] = bv[u];
      }
    }
    __syncthreads();
    short8 a[4];
#pragma unroll
    for (int mi = 0; mi < 4; ++mi)
      a[mi] = *(const short8*)(As + (wm * 64 + mi * 16 + l16) * 32 + qg * 8);
#pragma unroll
    for (int ni = 0; ni < 4; ++ni) {
      int n = wn * 64 + ni * 16 + l16;
      short8 b = *(const short8*)(Bs + (n << 5) + ((qg ^ (n & 3)) << 3));
#pragma unroll
      for (int mi = 0; mi < 4; ++mi)
        acc[mi][ni] = __builtin_amdgcn_mfma_f32_16x16x32_bf16(a[mi], b, acc[mi][ni], 0, 0, 0);
    }
  }
#pragma unroll
  for (int ni = 0; ni < 4; ++ni) {
    int col = n0 + wn * 64 + ni * 16 + l16;
    float bv = bias ? loadf(bias, col, f32) : 0.0f;
#pragma unroll
    for (int mi = 0; mi < 4; ++mi) {
      int row = m0 + wm * 64 + mi * 16 + qg * 4;
#pragma unroll
      for (int r = 0; r < 4; ++r) {
        size_t idx = (size_t)(c_row0 + row + r) * N + col;
        float val = acc[mi][ni][r] + bv;
        if (c32) ((float*)C)[idx] = val;
        else     ((short*)C)[idx] = f2b(val);
      }
    }
  }
}

// ---------- in-place RMSNorm + RoPE on q,k inside qkv[t][9216]; 1/sqrt(128) folded into q
__global__ __launch_bounds__(128)
void norm_rope(short* __restrict__ qkv, const int* __restrict__ ids,
               const void* __restrict__ nqw, const void* __restrict__ nkw,
               const void* __restrict__ naqw, const void* __restrict__ nakw,
               const int* __restrict__ dflag) {
  const bool f32 = (*dflag != 0);
  const int t = blockIdx.x, h = blockIdx.y, d = threadIdx.x;
  const size_t base = (size_t)t * 9216 + h * 128 + d;
  float qv = b2f(qkv[base]);
  float kv = b2f(qkv[base + 3072]);
  float sq = qv * qv, sk = kv * kv;
#pragma unroll
  for (int o = 1; o < 64; o <<= 1) { sq += __shfl_xor(sq, o); sk += __shfl_xor(sk, o); }
  __shared__ float red[2][2];
  if ((d & 63) == 0) { red[0][d >> 6] = sq; red[1][d >> 6] = sk; }
  __syncthreads();
  sq = red[0][0] + red[0][1];
  sk = red[1][0] + red[1][1];
  float rq = rsqrtf(sq * (1.0f / 128.0f) + 1e-5f);
  float rk = rsqrtf(sk * (1.0f / 128.0f) + 1e-5f);
  const bool txt = t < 512;
  float qn = qv * rq * loadf(txt ? naqw : nqw, d, f32);
  float kn = kv * rk * loadf(txt ? nakw : nkw, d, f32);
  // rope axes (16,56,56): 8 + 28 + 28 freq pairs
  int p = d >> 1, axis; float expo;
  if (p < 8)       { axis = 0; expo = (float)(2 * p) * (1.0f / 16.0f); }
  else if (p < 36) { axis = 1; expo = (float)(2 * (p - 8)) * (1.0f / 56.0f); }
  else             { axis = 2; expo = (float)(2 * (p - 36)) * (1.0f / 56.0f); }
  float freq = powf(10000.0f, -expo);
  float ang = (float)ids[t * 3 + axis] * freq;
  float s, c; sincosf(ang, &s, &c);
  float qp = __shfl_xor(qn, 1), kp = __shfl_xor(kn, 1);
  float sgn = (d & 1) ? 1.0f : -1.0f;
  float qo = qn * c + sgn * qp * s;
  float ko = kn * c + sgn * kp * s;
  qkv[base]        = f2b(qo * 0.08838834764831845f);
  qkv[base + 3072] = f2b(ko);
}

// ---------- flash attention over qkv[t][9216]: q at h*128, k at 3072+h*128, v at 6144+h*128.
// Q-tile 128, K-tile 128; 4 waves each own 32 q-rows (wave-private online softmax).
// QPs holds Q (hoisted to regs) then P; KVs holds K then V^T (transposed during staging).
__global__ __launch_bounds__(256, 2)
void attn_fa(const short* __restrict__ qkv, short* __restrict__ attn) {
  __shared__ short QPs[128 * 128];
  __shared__ short KVs[128 * 128];
  const int qt = blockIdx.x, h = blockIdx.y;
  const int tid = threadIdx.x, lane = tid & 63, w = tid >> 6;
  const int qg = lane >> 4, l16 = lane & 15;
  const int q0 = qt << 7;
  const int srow = tid >> 4, sc = tid & 15;

  {
    const short* Qg = qkv + (size_t)q0 * 9216 + h * 128;
#pragma unroll
    for (int j = 0; j < 8; ++j) {
      int row = j * 16 + srow;
      short8 v = *(const short8*)(Qg + (size_t)row * 9216 + sc * 8);
      *(short8*)(QPs + row * 128 + ((sc ^ (row & 7)) << 3)) = v;
    }
  }
  __syncthreads();
  short8 aq[2][4];
#pragma unroll
  for (int mi = 0; mi < 2; ++mi)
#pragma unroll
    for (int kc = 0; kc < 4; ++kc) {
      int row = w * 32 + mi * 16 + l16;
      aq[mi][kc] = *(const short8*)(QPs + row * 128 + (((kc * 4 + qg) ^ (row & 7)) << 3));
    }

  floatx4 acc_o[2][8];
#pragma unroll
  for (int mi = 0; mi < 2; ++mi)
#pragma unroll
    for (int nd = 0; nd < 8; ++nd) acc_o[mi][nd] = (floatx4){0.f, 0.f, 0.f, 0.f};
  float m_i[2][4], l_i[2][4];
#pragma unroll
  for (int mi = 0; mi < 2; ++mi)
#pragma unroll
    for (int r = 0; r < 4; ++r) { m_i[mi][r] = -1e30f; l_i[mi][r] = 0.0f; }

  for (int kt = 0; kt < 20; ++kt) {
    __syncthreads();  // prev iteration's PV reads done
    {
      const short* Kg = qkv + (size_t)kt * 128 * 9216 + 3072 + h * 128;
#pragma unroll
      for (int j = 0; j < 8; ++j) {
        int row = j * 16 + srow;  // key token
        short8 v = *(const short8*)(Kg + (size_t)row * 9216 + sc * 8);
        *(short8*)(KVs + row * 128 + ((sc ^ (row & 7)) << 3)) = v;
      }
    }
    __syncthreads();
    floatx4 acc_s[2][8];
#pragma unroll
    for (int mi = 0; mi < 2; ++mi)
#pragma unroll
      for (int ni = 0; ni < 8; ++ni) acc_s[mi][ni] = (floatx4){0.f, 0.f, 0.f, 0.f};
#pragma unroll
    for (int kc = 0; kc < 4; ++kc) {
#pragma unroll
      for (int ni = 0; ni < 8; ++ni) {
        int row = ni * 16 + l16;  // key
        short8 b = *(const short8*)(KVs + row * 128 + (((kc * 4 + qg) ^ (row & 7)) << 3));
        acc_s[0][ni] = __builtin_amdgcn_mfma_f32_16x16x32_bf16(aq[0][kc], b, acc_s[0][ni], 0, 0, 0);
        acc_s[1][ni] = __builtin_amdgcn_mfma_f32_16x16x32_bf16(aq[1][kc], b, acc_s[1][ni], 0, 0, 0);
      }
    }
    float alpha[2][4];
#pragma unroll
    for (int mi = 0; mi < 2; ++mi) {
#pragma unroll
      for (int r = 0; r < 4; ++r) {
        float mx = acc_s[mi][0][r];
#pragma unroll
        for (int ni = 1; ni < 8; ++ni) mx = fmaxf(mx, acc_s[mi][ni][r]);
        mx = fmaxf(mx, __shfl_xor(mx, 1));
        mx = fmaxf(mx, __shfl_xor(mx, 2));
        mx = fmaxf(mx, __shfl_xor(mx, 4));
        mx = fmaxf(mx, __shfl_xor(mx, 8));
        float mn = fmaxf(m_i[mi][r], mx);
        alpha[mi][r] = __expf(m_i[mi][r] - mn);
        m_i[mi][r] = mn;
      }
    }
#pragma unroll
    for (int mi = 0; mi < 2; ++mi) {
      float rs[4] = {0.f, 0.f, 0.f, 0.f};
#pragma unroll
      for (int ni = 0; ni < 8; ++ni) {
#pragma unroll
        for (int r = 0; r < 4; ++r) {
          float pv = __expf(acc_s[mi][ni][r] - m_i[mi][r]);
          rs[r] += pv;
          int row = w * 32 + mi * 16 + qg * 4 + r;  // wave-private
          int col = ni * 16 + l16;
          QPs[row * 128 + (((col >> 3) ^ (row & 7)) << 3) + (col & 7)] = f2b(pv);
        }
      }
#pragma unroll
      for (int r = 0; r < 4; ++r) {
        float t = rs[r];
        t += __shfl_xor(t, 1); t += __shfl_xor(t, 2);
        t += __shfl_xor(t, 4); t += __shfl_xor(t, 8);
        l_i[mi][r] = alpha[mi][r] * l_i[mi][r] + t;
      }
#pragma unroll
      for (int nd = 0; nd < 8; ++nd)
#pragma unroll
        for (int r = 0; r < 4; ++r) acc_o[mi][nd][r] *= alpha[mi][r];
    }
    __syncthreads();  // K reads done before V overwrites KVs
    {
      const short* Vg = qkv + (size_t)kt * 128 * 9216 + 6144 + h * 128;
#pragma unroll
      for (int j = 0; j < 8; ++j) {
        int r = j * 16 + srow;  // key token
        short8 vv = *(const short8*)(Vg + (size_t)r * 9216 + sc * 8);
#pragma unroll
        for (int s = 0; s < 8; ++s) {
          int u = (s + sc) & 7;  // rotate to spread banks
          int d = sc * 8 + u;
          KVs[d * 128 + (((r >> 3) ^ (d & 7)) << 3) + (r & 7)] = vv[u];
        }
      }
    }
    __syncthreads();
#pragma unroll
    for (int kc = 0; kc < 4; ++kc) {
      int prow0 = w * 32 + l16;
      short8 ap0 = *(const short8*)(QPs + prow0 * 128 + (((kc * 4 + qg) ^ (prow0 & 7)) << 3));
      int prow1 = prow0 + 16;
      short8 ap1 = *(const short8*)(QPs + prow1 * 128 + (((kc * 4 + qg) ^ (prow1 & 7)) << 3));
#pragma unroll
      for (int nd = 0; nd < 8; ++nd) {
        int row = nd * 16 + l16;  // d index
        short8 b = *(const short8*)(KVs + row * 128 + (((kc * 4 + qg) ^ (row & 7)) << 3));
        acc_o[0][nd] = __builtin_amdgcn_mfma_f32_16x16x32_bf16(ap0, b, acc_o[0][nd], 0, 0, 0);
        acc_o[1][nd] = __builtin_amdgcn_mfma_f32_16x16x32_bf16(ap1, b, acc_o[1][nd], 0, 0, 0);
      }
    }
  }
#pragma unroll
  for (int mi = 0; mi < 2; ++mi) {
    float inv[4];
#pragma unroll
    for (int r = 0; r < 4; ++r) inv[r] = 1.0f / l_i[mi][r];
#pragma unroll
    for (int nd = 0; nd < 8; ++nd) {
#pragma unroll
      for (int r = 0; r < 4; ++r) {
        int row = q0 + w * 32 + mi * 16 + qg * 4 + r;
        int col = h * 128 + nd * 16 + l16;
        attn[(size_t)row * 3072 + col] = f2b(acc_o[mi][nd][r] * inv[r]);
      }
    }
  }
}

extern "C" void kernel_launch(void* const* d_in, const int* in_sizes, int n_in,
                              void* d_out, int out_size, void* d_ws, size_t ws_size,
                              hipStream_t stream) {
  (void)in_sizes; (void)n_in; (void)out_size; (void)ws_size;
  const void* hidden    = d_in[0];
  const void* enc       = d_in[1];
  const int*  ids       = (const int*)d_in[2];
  const void* w_qkv     = d_in[3];
  const void* w_add_qkv = d_in[4];
  const void* b_add_qkv = d_in[5];
  const void* w_out     = d_in[6];
  const void* b_out     = d_in[7];
  const void* w_add_out = d_in[8];
  const void* b_add_out = d_in[9];
  const void* nqw  = d_in[10];
  const void* nkw  = d_in[11];
  const void* naqw = d_in[12];
  const void* nakw = d_in[13];

  int*   dflag = (int*)d_ws;
  short* qkv   = (short*)((char*)d_ws + 256);   // [2560][9216] bf16
  short* attn  = qkv + (size_t)2560 * 9216;     // [2560][3072] bf16
  // total ws: 256 + 62,914,560 bytes ~= 60 MB

  detect_dtype<<<1, 256, 0, stream>>>((const unsigned short*)w_qkv, dflag);
  // QKV projections: enc rows 0..511 (with bias), img rows 512..2559
  gemm_bt<<<dim3(72, 4), 256, 0, stream>>>(enc, 0, w_add_qkv, b_add_qkv, qkv, 0, 9216, 3072, dflag, 1, 0);
  gemm_bt<<<dim3(72, 16), 256, 0, stream>>>(hidden, 0, w_qkv, nullptr, qkv, 512, 9216, 3072, dflag, 1, 0);
  // in-place norm + rope
  norm_rope<<<dim3(2560, 24), 128, 0, stream>>>(qkv, ids, nqw, nkw, naqw, nakw, dflag);
  // attention
  attn_fa<<<dim3(20, 24), 256, 0, stream>>>(qkv, attn);
  // output projections: img_out (rows 0..) then enc_out (at element 2048*3072)
  gemm_bt<<<dim3(24, 16), 256, 0, stream>>>(attn, 512, w_out, b_out, d_out, 0, 3072, 3072, dflag, 0, 1);
  gemm_bt<<<dim3(24, 4), 256, 0, stream>>>(attn, 0, w_add_out, b_add_out, d_out, 2048, 3072, 3072, dflag, 0, 1);
}